// Round 1
// baseline (9325.313 us; speedup 1.0000x reference)
//
#include <hip/hip_runtime.h>
#include <math.h>

#define TT 35
#define BB 64
#define EMB 1500
#define HID 1500
#define VOCAB 10000
#define ZN 6000            // 4*HID
#define KT 3000            // EMB+HID
#define KSPLIT 5           // K-split for lstm gemm (600 each)
#define FORGET_BIAS 1.0f

__device__ __forceinline__ float sigmoidf_(float x) { return 1.0f / (1.0f + expf(-x)); }

// ---------------- embedding gather: one block per (t,b) token ----------------
__global__ __launch_bounds__(256) void embed_kernel(const int* __restrict__ x,
                                                    const float* __restrict__ emb,
                                                    float* __restrict__ xe) {
    int tok = blockIdx.x;               // 0..TT*BB-1, t-major (matches x flat layout)
    int tid = threadIdx.x;
    int v = x[tok];
    const float2* src = (const float2*)(emb + (size_t)v * EMB);   // 1500*4B rows are 8B-aligned
    float2* dst = (float2*)(xe + (size_t)tok * EMB);
    for (int i = tid; i < EMB / 2; i += 256) dst[i] = src[i];
}

// ---------------- LSTM z-GEMM: z[64 x 6000] = [A0|A1](64x3000) @ W(3000x6000) ----------------
// grid (94, KSPLIT), block 256. Writes K-split partials zp[KSPLIT][64][6000] (deterministic).
__global__ __launch_bounds__(256) void lstm_gemm(const float* __restrict__ A0,
                                                 const float* __restrict__ A1,
                                                 const float* __restrict__ W,
                                                 float* __restrict__ zp) {
    __shared__ float As[64 * 21];       // 64 rows x 20 k, stride 21 (odd -> conflict-free reads)
    int tid = threadIdx.x;
    int tx = tid & 15;                  // float4 column group
    int ty = tid >> 4;                  // row group (rows ty, ty+16, ty+32, ty+48)
    int n0 = blockIdx.x * 64 + tx * 4;
    bool nok = (n0 < ZN);               // last block covers 48 cols
    int kbase = blockIdx.y * (KT / KSPLIT);   // 600 per split
    float4 acc[4];
#pragma unroll
    for (int r = 0; r < 4; ++r) acc[r] = make_float4(0.f, 0.f, 0.f, 0.f);

    for (int it = 0; it < (KT / KSPLIT) / 20; ++it) {   // 30 iters of Kc=20
        int k0 = kbase + it * 20;
#pragma unroll
        for (int l = 0; l < 5; ++l) {   // 1280 elements / 256 threads
            int j = tid + 256 * l;
            int m = j / 20, k = j % 20;
            int kk = k0 + k;
            float v = (kk < HID) ? A0[m * EMB + kk] : A1[m * HID + (kk - HID)];
            As[m * 21 + k] = v;
        }
        __syncthreads();
        if (nok) {
#pragma unroll
            for (int k = 0; k < 20; ++k) {
                const float4 w = *(const float4*)&W[(k0 + k) * ZN + n0];
#pragma unroll
                for (int r = 0; r < 4; ++r) {
                    float a = As[(ty + 16 * r) * 21 + k];
                    acc[r].x += a * w.x; acc[r].y += a * w.y;
                    acc[r].z += a * w.z; acc[r].w += a * w.w;
                }
            }
        }
        __syncthreads();
    }
    if (nok) {
        float* zb = zp + (size_t)blockIdx.y * (BB * ZN);
#pragma unroll
        for (int r = 0; r < 4; ++r) {
            int row = ty + 16 * r;
            *(float4*)&zb[row * ZN + n0] = acc[r];
        }
    }
}

// ---------------- gate elementwise: sums K-split partials, applies LSTM cell ----------------
__global__ __launch_bounds__(256) void lstm_gate(const float* __restrict__ zp,
                                                 const float* __restrict__ b,
                                                 float* __restrict__ c,
                                                 float* __restrict__ h,
                                                 float* __restrict__ out_h) {
    int i = blockIdx.x * 256 + threadIdx.x;
    if (i >= BB * HID) return;
    int row = i / HID, col = i % HID;
    float zi = b[col], zj = b[HID + col], zf = b[2 * HID + col], zo = b[3 * HID + col];
#pragma unroll
    for (int ks = 0; ks < KSPLIT; ++ks) {
        const float* zb = zp + (size_t)ks * (BB * ZN) + row * ZN;
        zi += zb[col]; zj += zb[HID + col]; zf += zb[2 * HID + col]; zo += zb[3 * HID + col];
    }
    float cn = c[i] * sigmoidf_(zf + FORGET_BIAS) + sigmoidf_(zi) * tanhf(zj);
    float hn = tanhf(cn) * sigmoidf_(zo);
    c[i] = cn;
    h[i] = hn;
    if (out_h) out_h[i] = hn;
}

// ---------------- logits GEMM: (64-row tile of outs) @ softmax_w + softmax_b ----------------
// grid (157, 5): 157 n-tiles of 64 over VOCAB=10000, 5 m-tiles of 64 over the 320-row chunk.
__global__ __launch_bounds__(256) void logits_gemm(const float* __restrict__ A,
                                                   const float* __restrict__ Wm,
                                                   const float* __restrict__ bias,
                                                   float* __restrict__ Cout) {
    __shared__ float As[64 * 21];
    int tid = threadIdx.x;
    int tx = tid & 15, ty = tid >> 4;
    int n0 = blockIdx.x * 64 + tx * 4;
    bool nok = (n0 < VOCAB);
    const float* Ab = A + (size_t)blockIdx.y * 64 * HID;
    float4 acc[4];
#pragma unroll
    for (int r = 0; r < 4; ++r) acc[r] = make_float4(0.f, 0.f, 0.f, 0.f);

    for (int it = 0; it < HID / 20; ++it) {    // 75 iters
        int k0 = it * 20;
#pragma unroll
        for (int l = 0; l < 5; ++l) {
            int j = tid + 256 * l;
            int m = j / 20, k = j % 20;
            As[m * 21 + k] = Ab[m * HID + k0 + k];
        }
        __syncthreads();
        if (nok) {
#pragma unroll
            for (int k = 0; k < 20; ++k) {
                const float4 w = *(const float4*)&Wm[(k0 + k) * VOCAB + n0];
#pragma unroll
                for (int r = 0; r < 4; ++r) {
                    float a = As[(ty + 16 * r) * 21 + k];
                    acc[r].x += a * w.x; acc[r].y += a * w.y;
                    acc[r].z += a * w.z; acc[r].w += a * w.w;
                }
            }
        }
        __syncthreads();
    }
    if (nok) {
        float4 bv = *(const float4*)&bias[n0];
#pragma unroll
        for (int r = 0; r < 4; ++r) {
            int row = blockIdx.y * 64 + ty + 16 * r;   // row within 320-chunk
            float4 o;
            o.x = acc[r].x + bv.x; o.y = acc[r].y + bv.y;
            o.z = acc[r].z + bv.z; o.w = acc[r].w + bv.w;
            *(float4*)&Cout[(size_t)row * VOCAB + n0] = o;
        }
    }
}

// ---------------- per-row log-softmax NLL: one block per row ----------------
__global__ __launch_bounds__(256) void nll_kernel(const float* __restrict__ logits,
                                                  const int* __restrict__ y,
                                                  float* __restrict__ nll,
                                                  int row_base) {
    __shared__ float red[256];
    int r = blockIdx.x;
    const float* lr = logits + (size_t)r * VOCAB;
    int tid = threadIdx.x;
    float lm = -INFINITY;
    for (int i = tid; i < VOCAB; i += 256) lm = fmaxf(lm, lr[i]);
    red[tid] = lm; __syncthreads();
    for (int s = 128; s > 0; s >>= 1) { if (tid < s) red[tid] = fmaxf(red[tid], red[tid + s]); __syncthreads(); }
    float m = red[0]; __syncthreads();
    float ls = 0.f;
    for (int i = tid; i < VOCAB; i += 256) ls += expf(lr[i] - m);
    red[tid] = ls; __syncthreads();
    for (int s = 128; s > 0; s >>= 1) { if (tid < s) red[tid] += red[tid + s]; __syncthreads(); }
    if (tid == 0) {
        int rg = row_base + r;
        int tgt = y[rg];
        nll[rg] = -(lr[tgt] - m - logf(red[0]));
    }
}

// ---------------- final: loss = sum(nll) / B ----------------
__global__ __launch_bounds__(256) void loss_kernel(const float* __restrict__ nll,
                                                   float* __restrict__ out) {
    __shared__ float red[256];
    int tid = threadIdx.x;
    float s = 0.f;
    for (int i = tid; i < TT * BB; i += 256) s += nll[i];
    red[tid] = s; __syncthreads();
    for (int st = 128; st > 0; st >>= 1) { if (tid < st) red[tid] += red[tid + st]; __syncthreads(); }
    if (tid == 0) out[0] = red[0] / (float)BB;
}

extern "C" void kernel_launch(void* const* d_in, const int* in_sizes, int n_in,
                              void* d_out, int out_size, void* d_ws, size_t ws_size,
                              hipStream_t stream) {
    const int*   x   = (const int*)d_in[0];
    const int*   y   = (const int*)d_in[1];
    const float* emb = (const float*)d_in[2];
    const float* W0  = (const float*)d_in[3];
    const float* b0  = (const float*)d_in[4];
    const float* W1  = (const float*)d_in[5];
    const float* b1  = (const float*)d_in[6];
    const float* sw  = (const float*)d_in[7];
    const float* sb  = (const float*)d_in[8];
    float* out = (float*)d_out;

    // workspace layout (floats), total ~12.23M floats ~= 48.9 MB
    float* ws = (float*)d_ws;
    float* xe     = ws;                      // TT*BB*EMB   = 3,360,000
    float* outs   = xe + 3360000;            // TT*BB*HID   = 3,360,000
    float* h0     = outs + 3360000;          // 96,000
    float* c0     = h0 + 96000;              // 96,000
    float* h1     = c0 + 96000;              // 96,000
    float* c1     = h1 + 96000;              // 96,000
    float* zp     = c1 + 96000;              // KSPLIT*BB*ZN = 1,920,000
    float* logits = zp + 1920000;            // 320*VOCAB   = 3,200,000
    float* nll    = logits + 3200000;        // TT*BB       = 2,240

    // zero the 4 recurrent state buffers (contiguous) — ws is poisoned each call
    hipMemsetAsync(h0, 0, (size_t)4 * 96000 * sizeof(float), stream);

    embed_kernel<<<TT * BB, 256, 0, stream>>>(x, emb, xe);

    dim3 blk(256);
    dim3 gz(94, KSPLIT);
    for (int t = 0; t < TT; ++t) {
        lstm_gemm<<<gz, blk, 0, stream>>>(xe + (size_t)t * BB * EMB, h0, W0, zp);
        lstm_gate<<<375, blk, 0, stream>>>(zp, b0, c0, h0, nullptr);
        lstm_gemm<<<gz, blk, 0, stream>>>(h0, h1, W1, zp);
        lstm_gate<<<375, blk, 0, stream>>>(zp, b1, c1, h1, outs + (size_t)t * BB * HID);
    }

    dim3 gl(157, 5);
    for (int ch = 0; ch < 7; ++ch) {          // 7 chunks of 320 rows = 2240
        logits_gemm<<<gl, blk, 0, stream>>>(outs + (size_t)ch * 320 * HID, sw, sb, logits);
        nll_kernel<<<320, blk, 0, stream>>>(logits, y, nll, ch * 320);
    }
    loss_kernel<<<1, blk, 0, stream>>>(nll, out);
}

// Round 2
// 4781.629 us; speedup vs baseline: 1.9502x; 1.9502x over previous
//
#include <hip/hip_runtime.h>
#include <math.h>

#define TT 35
#define BB 64
#define EMB 1500
#define HID 1500
#define VOCAB 10000
#define KT 3008          // EMB+HID padded to x32
#define KI 94            // KT/32
#define KLP 1504         // HID padded to x32 (logits K)
#define FORGET_BIAS 1.0f

typedef __bf16 bf16x8 __attribute__((ext_vector_type(8)));
typedef float f32x4 __attribute__((ext_vector_type(4)));

__device__ __forceinline__ unsigned short f2bf(float f) {
    unsigned int u = __builtin_bit_cast(unsigned int, f);
    u += 0x7fffu + ((u >> 16) & 1u);           // RNE
    return (unsigned short)(u >> 16);
}
__device__ __forceinline__ float sigmoidf_(float x) { return 1.0f / (1.0f + expf(-x)); }

// ---- W (K x N fp32) -> WT (N x KP bf16), zero-fill k in [K,KP) ----
__global__ __launch_bounds__(256) void convT(const float* __restrict__ W,
                                             unsigned short* __restrict__ WT,
                                             int K, int N, int KP) {
    __shared__ float tile[32][33];
    int tx = threadIdx.x, ty = threadIdx.y;    // 32 x 8
    int n0 = blockIdx.x * 32, k0 = blockIdx.y * 32;
#pragma unroll
    for (int i = 0; i < 4; ++i) {
        int k = k0 + ty + 8 * i, n = n0 + tx;
        tile[ty + 8 * i][tx] = (k < K && n < N) ? W[(size_t)k * N + n] : 0.f;
    }
    __syncthreads();
#pragma unroll
    for (int i = 0; i < 4; ++i) {
        int n = n0 + ty + 8 * i, k = k0 + tx;
        if (n < N) WT[(size_t)n * KP + k] = f2bf(tile[tx][ty + 8 * i]);
    }
}

// ---- embedding gather -> bf16 into per-step A0 buffers (cols 0..1499) ----
__global__ __launch_bounds__(256) void embed_kernel(const int* __restrict__ x,
                                                    const float* __restrict__ emb,
                                                    unsigned short* __restrict__ A0) {
    int tok = blockIdx.x;                       // t*BB + b (t-major, matches x layout)
    int v = x[tok];
    const float* src = emb + (size_t)v * EMB;
    unsigned short* dst = A0 + (size_t)tok * KT;
    for (int i = threadIdx.x; i < EMB; i += 256) dst[i] = f2bf(src[i]);
}

// ---- fused LSTM step: z = A(64xKT) @ W^T cols for 16 hidden cols x 4 gates, then gate math ----
// grid 94 (16 hidden cols each), block 1024 = 16 waves = 4 m-tiles x 4 k-groups
__global__ __launch_bounds__(1024) void lstm_fused(const unsigned short* __restrict__ A,   // 64 x KT
                                                   const unsigned short* __restrict__ WT,  // 6000 x KT
                                                   const float* __restrict__ bias,         // 6000
                                                   float* __restrict__ cst,                // 64 x HID
                                                   unsigned short* __restrict__ d1, int s1,
                                                   unsigned short* __restrict__ d2, int s2) {
    __shared__ float red[16][64][17];           // pad 17: conflict-free b128
    int tid = threadIdx.x;
    int wv = tid >> 6, lane = tid & 63;
    int mt = wv & 3, kg = wv >> 2;
    int quad = lane >> 4, l16 = lane & 15;
    int col = blockIdx.x * 16 + l16;            // hidden col (valid if <1500)

    f32x4 acc[4];
#pragma unroll
    for (int g = 0; g < 4; ++g) acc[g] = (f32x4){0.f, 0.f, 0.f, 0.f};

    int it0 = (KI * kg) >> 2, it1 = (KI * (kg + 1)) >> 2;

    const unsigned short* ap = A + (size_t)(mt * 16 + l16) * KT + quad * 8 + it0 * 32;
    const unsigned short* bp0, *bp1, *bp2, *bp3;
    {
        int n0 = 0 * HID + col;                       // i
        int n1 = 1 * HID + col;                       // j
        int n2 = 2 * HID + col;                       // f
        int n3 = 3 * HID + col; if (n3 > 5999) n3 = 5999;  // o (clamp pad lanes)
        bp0 = WT + (size_t)n0 * KT + quad * 8 + it0 * 32;
        bp1 = WT + (size_t)n1 * KT + quad * 8 + it0 * 32;
        bp2 = WT + (size_t)n2 * KT + quad * 8 + it0 * 32;
        bp3 = WT + (size_t)n3 * KT + quad * 8 + it0 * 32;
    }
    for (int it = it0; it < it1; ++it) {
        bf16x8 a  = *(const bf16x8*)ap;
        bf16x8 b0 = *(const bf16x8*)bp0;
        bf16x8 b1 = *(const bf16x8*)bp1;
        bf16x8 b2 = *(const bf16x8*)bp2;
        bf16x8 b3 = *(const bf16x8*)bp3;
        acc[0] = __builtin_amdgcn_mfma_f32_16x16x32_bf16(a, b0, acc[0], 0, 0, 0);
        acc[1] = __builtin_amdgcn_mfma_f32_16x16x32_bf16(a, b1, acc[1], 0, 0, 0);
        acc[2] = __builtin_amdgcn_mfma_f32_16x16x32_bf16(a, b2, acc[2], 0, 0, 0);
        acc[3] = __builtin_amdgcn_mfma_f32_16x16x32_bf16(a, b3, acc[3], 0, 0, 0);
        ap += 32; bp0 += 32; bp1 += 32; bp2 += 32; bp3 += 32;
    }
#pragma unroll
    for (int g = 0; g < 4; ++g)
#pragma unroll
        for (int r = 0; r < 4; ++r) red[wv][lane][g * 4 + r] = acc[g][r];
    __syncthreads();
    if (kg == 0) {
#pragma unroll
        for (int k2 = 1; k2 < 4; ++k2)
#pragma unroll
            for (int g = 0; g < 4; ++g)
#pragma unroll
                for (int r = 0; r < 4; ++r) acc[g][r] += red[k2 * 4 + mt][lane][g * 4 + r];
        if (col < HID) {
            float bi = bias[col], bj = bias[HID + col];
            float bf_ = bias[2 * HID + col], bo = bias[3 * HID + col];
#pragma unroll
            for (int r = 0; r < 4; ++r) {
                int row = mt * 16 + quad * 4 + r;
                float zi = acc[0][r] + bi;
                float zj = acc[1][r] + bj;
                float zf = acc[2][r] + bf_;
                float zo = acc[3][r] + bo;
                int ci = row * HID + col;
                float cn = cst[ci] * sigmoidf_(zf + FORGET_BIAS) + sigmoidf_(zi) * tanhf(zj);
                float hn = tanhf(cn) * sigmoidf_(zo);
                cst[ci] = cn;
                unsigned short hb = f2bf(hn);
                d1[(size_t)row * s1 + col] = hb;
                if (d2) d2[(size_t)row * s2 + col] = hb;
            }
        }
    }
}

// ---- logits MFMA: chunk A (320 x KLP bf16) @ swT -> logits fp32 (320 x VOCAB) ----
// grid (157, 5), block 256 = 4 waves (one 16-row m-tile each, 4 n-subtiles)
__global__ __launch_bounds__(256) void logits_mfma(const unsigned short* __restrict__ A,
                                                   const unsigned short* __restrict__ WT,  // 10000 x KLP
                                                   const float* __restrict__ bias,
                                                   float* __restrict__ C) {
    int tid = threadIdx.x;
    int wv = tid >> 6, lane = tid & 63;
    int quad = lane >> 4, l16 = lane & 15;
    int row0 = blockIdx.y * 64 + wv * 16;
    int n0 = blockIdx.x * 64;
    f32x4 acc[4];
#pragma unroll
    for (int s = 0; s < 4; ++s) acc[s] = (f32x4){0.f, 0.f, 0.f, 0.f};
    const unsigned short* ap = A + (size_t)(row0 + l16) * KLP + quad * 8;
    const unsigned short* bp[4];
#pragma unroll
    for (int s = 0; s < 4; ++s) {
        int n = n0 + s * 16 + l16; if (n > VOCAB - 1) n = VOCAB - 1;
        bp[s] = WT + (size_t)n * KLP + quad * 8;
    }
    for (int it = 0; it < KLP / 32; ++it) {
        bf16x8 a  = *(const bf16x8*)ap;
        bf16x8 b0 = *(const bf16x8*)bp[0];
        bf16x8 b1 = *(const bf16x8*)bp[1];
        bf16x8 b2 = *(const bf16x8*)bp[2];
        bf16x8 b3 = *(const bf16x8*)bp[3];
        acc[0] = __builtin_amdgcn_mfma_f32_16x16x32_bf16(a, b0, acc[0], 0, 0, 0);
        acc[1] = __builtin_amdgcn_mfma_f32_16x16x32_bf16(a, b1, acc[1], 0, 0, 0);
        acc[2] = __builtin_amdgcn_mfma_f32_16x16x32_bf16(a, b2, acc[2], 0, 0, 0);
        acc[3] = __builtin_amdgcn_mfma_f32_16x16x32_bf16(a, b3, acc[3], 0, 0, 0);
        ap += 32; bp[0] += 32; bp[1] += 32; bp[2] += 32; bp[3] += 32;
    }
#pragma unroll
    for (int s = 0; s < 4; ++s) {
        int cn_ = n0 + s * 16 + l16;
        if (cn_ < VOCAB) {
            float bv = bias[cn_];
#pragma unroll
            for (int r = 0; r < 4; ++r) {
                int row = row0 + quad * 4 + r;
                C[(size_t)row * VOCAB + cn_] = acc[s][r] + bv;
            }
        }
    }
}

// ---- per-row log-softmax NLL ----
__global__ __launch_bounds__(256) void nll_kernel(const float* __restrict__ logits,
                                                  const int* __restrict__ y,
                                                  float* __restrict__ nll, int row_base) {
    __shared__ float red[256];
    int r = blockIdx.x;
    const float* lr = logits + (size_t)r * VOCAB;
    int tid = threadIdx.x;
    float lm = -INFINITY;
    for (int i = tid; i < VOCAB; i += 256) lm = fmaxf(lm, lr[i]);
    red[tid] = lm; __syncthreads();
    for (int s = 128; s > 0; s >>= 1) { if (tid < s) red[tid] = fmaxf(red[tid], red[tid + s]); __syncthreads(); }
    float m = red[0]; __syncthreads();
    float ls = 0.f;
    for (int i = tid; i < VOCAB; i += 256) ls += expf(lr[i] - m);
    red[tid] = ls; __syncthreads();
    for (int s = 128; s > 0; s >>= 1) { if (tid < s) red[tid] += red[tid + s]; __syncthreads(); }
    if (tid == 0) {
        int rg = row_base + r;
        nll[rg] = -(lr[y[rg]] - m - logf(red[0]));
    }
}

__global__ __launch_bounds__(256) void loss_kernel(const float* __restrict__ nll,
                                                   float* __restrict__ out) {
    __shared__ float red[256];
    int tid = threadIdx.x;
    float s = 0.f;
    for (int i = tid; i < TT * BB; i += 256) s += nll[i];
    red[tid] = s; __syncthreads();
    for (int st = 128; st > 0; st >>= 1) { if (tid < st) red[tid] += red[tid + st]; __syncthreads(); }
    if (tid == 0) out[0] = red[0] / (float)BB;
}

extern "C" void kernel_launch(void* const* d_in, const int* in_sizes, int n_in,
                              void* d_out, int out_size, void* d_ws, size_t ws_size,
                              hipStream_t stream) {
    const int*   x   = (const int*)d_in[0];
    const int*   y   = (const int*)d_in[1];
    const float* emb = (const float*)d_in[2];
    const float* W0  = (const float*)d_in[3];
    const float* b0  = (const float*)d_in[4];
    const float* W1  = (const float*)d_in[5];
    const float* b1  = (const float*)d_in[6];
    const float* sw  = (const float*)d_in[7];
    const float* sb  = (const float*)d_in[8];
    float* out = (float*)d_out;

    // ---- workspace layout (bytes, all 16B aligned); total ~130.5 MB ----
    char* p = (char*)d_ws;
    unsigned short* A0   = (unsigned short*)p; p += (size_t)TT * BB * KT * 2;   // 13,475,840
    unsigned short* A1   = (unsigned short*)p; p += (size_t)2 * BB * KT * 2;    //    770,048 (double buffer)
    unsigned short* outs = (unsigned short*)p; p += (size_t)TT * BB * KLP * 2;  //  6,737,920
    float* c0 = (float*)p; p += (size_t)BB * HID * 4;                           //    384,000
    float* c1 = (float*)p; p += (size_t)BB * HID * 4;                           //    384,000
    size_t zero_bytes = (size_t)(p - (char*)d_ws);                              // 21,751,808
    unsigned short* WbT0 = (unsigned short*)p; p += (size_t)6000 * KT * 2;      // 36,096,000
    unsigned short* WbT1 = (unsigned short*)p; p += (size_t)6000 * KT * 2;      // 36,096,000
    unsigned short* swT  = (unsigned short*)p; p += (size_t)VOCAB * KLP * 2;    // 30,080,000
    float* logits = (float*)p; p += (size_t)320 * VOCAB * 4;                    // 12,800,000
    float* nll    = (float*)p;                                                  //      8,960

    hipMemsetAsync(d_ws, 0, zero_bytes, stream);   // A buffers (incl. pads + h init) + outs + c states

    dim3 cblk(32, 8);
    convT<<<dim3(188, 94), cblk, 0, stream>>>(W0, WbT0, 3000, 6000, KT);
    convT<<<dim3(188, 94), cblk, 0, stream>>>(W1, WbT1, 3000, 6000, KT);
    convT<<<dim3(313, 47), cblk, 0, stream>>>(sw, swT, HID, VOCAB, KLP);

    embed_kernel<<<TT * BB, 256, 0, stream>>>(x, emb, A0);

    for (int t = 0; t < TT; ++t) {
        unsigned short* A0t = A0 + (size_t)t * BB * KT;
        unsigned short* A1c = A1 + (size_t)(t & 1) * BB * KT;
        unsigned short* A1n = A1 + (size_t)((t + 1) & 1) * BB * KT;
        unsigned short* h0next = (t < TT - 1) ? (A0 + (size_t)(t + 1) * BB * KT + EMB) : nullptr;
        // layer 0: h0 -> A1cur cols [0,1500)  and  next step's A0 cols [1500,3000)
        lstm_fused<<<94, 1024, 0, stream>>>(A0t, WbT0, b0, c0, A1c, KT, h0next, KT);
        // layer 1: h1 -> A1next cols [1500,3000)  and  outs row block t
        lstm_fused<<<94, 1024, 0, stream>>>(A1c, WbT1, b1, c1, A1n + HID, KT,
                                            outs + (size_t)t * BB * KLP, KLP);
    }

    for (int ch = 0; ch < 7; ++ch) {
        logits_mfma<<<dim3(157, 5), 256, 0, stream>>>(outs + (size_t)ch * 320 * KLP, swT, sb, logits);
        nll_kernel<<<320, 256, 0, stream>>>(logits, y, nll, ch * 320);
    }
    loss_kernel<<<1, 256, 0, stream>>>(nll, out);
}